// Round 1
// baseline (436.241 us; speedup 1.0000x reference)
//
#include <hip/hip_runtime.h>
#include <math.h>

// Router: logits = hidden[16384,4096] @ W[64,4096]^T + b; top-2 + softmax.
// Output layout (all f32, concatenated): logits[16384*64] | indices[16384*2] | weights[16384*2]

namespace {

constexpr int Hdim = 4096;   // hidden size (K)
constexpr int Edim = 64;     // experts (N)
constexpr int BM   = 64;     // rows per block
constexpr int BK   = 32;     // k-tile
constexpr int LDT  = 68;     // padded LDS stride (68*4=272B, 16B-aligned, 4-way max conflict)
constexpr int TILE = BK * LDT;  // floats per LDS tile buffer

__global__ __launch_bounds__(256)
void router_kernel(const float* __restrict__ hid,
                   const float* __restrict__ Wm,
                   const float* __restrict__ bias,
                   float* __restrict__ out,
                   int nrows)
{
    // smem: sA double buffer [2][BK][LDT] (A^T: [k][m]), sB double buffer (W^T tile: [k][e])
    // epilogue reuses the sA region as logits[64][LDT] (64*68=4352 = 2*TILE floats exactly)
    __shared__ float smem[4 * TILE];
    float* sA = smem;
    float* sB = smem + 2 * TILE;

    const int tid = threadIdx.x;
    const int tx  = tid & 15;        // expert group: experts tx*4..tx*4+3
    const int ty  = tid >> 4;        // row group:    rows   ty*4..ty*4+3
    const int rowBase = blockIdx.x * BM;

    // staging mapping: each thread loads 2 float4 of A and 2 of W per k-step
    const int srow = tid >> 3;          // 0..31 (row / expert index, +32 for second)
    const int skq  = (tid & 7) * 4;     // k offset within tile: 0,4,...,28

    const float* aptr0 = hid + (size_t)(rowBase + srow) * Hdim + skq;
    const float* aptr1 = aptr0 + (size_t)32 * Hdim;
    const float* bptr0 = Wm  + (size_t)srow * Hdim + skq;
    const float* bptr1 = bptr0 + (size_t)32 * Hdim;

    float4 ra0, ra1, rb0, rb1;

    // prologue: load k-tile 0
    ra0 = *(const float4*)(aptr0);
    ra1 = *(const float4*)(aptr1);
    rb0 = *(const float4*)(bptr0);
    rb1 = *(const float4*)(bptr1);

    // store staged regs into LDS buffer `buf` (transposed: [k][m] / [k][e])
    auto store_tile = [&](int buf) {
        float* A = sA + buf * TILE;
        float* B = sB + buf * TILE;
        A[(skq + 0) * LDT + srow]      = ra0.x;
        A[(skq + 1) * LDT + srow]      = ra0.y;
        A[(skq + 2) * LDT + srow]      = ra0.z;
        A[(skq + 3) * LDT + srow]      = ra0.w;
        A[(skq + 0) * LDT + srow + 32] = ra1.x;
        A[(skq + 1) * LDT + srow + 32] = ra1.y;
        A[(skq + 2) * LDT + srow + 32] = ra1.z;
        A[(skq + 3) * LDT + srow + 32] = ra1.w;
        B[(skq + 0) * LDT + srow]      = rb0.x;
        B[(skq + 1) * LDT + srow]      = rb0.y;
        B[(skq + 2) * LDT + srow]      = rb0.z;
        B[(skq + 3) * LDT + srow]      = rb0.w;
        B[(skq + 0) * LDT + srow + 32] = rb1.x;
        B[(skq + 1) * LDT + srow + 32] = rb1.y;
        B[(skq + 2) * LDT + srow + 32] = rb1.z;
        B[(skq + 3) * LDT + srow + 32] = rb1.w;
    };

    store_tile(0);
    __syncthreads();

    float acc[4][4];
    #pragma unroll
    for (int i = 0; i < 4; ++i)
        #pragma unroll
        for (int j = 0; j < 4; ++j) acc[i][j] = 0.0f;

    constexpr int NSTEP = Hdim / BK;  // 128
    for (int step = 0; step < NSTEP; ++step) {
        const int cur = step & 1;
        const bool more = (step + 1) < NSTEP;
        if (more) {
            const int off = (step + 1) * BK;
            ra0 = *(const float4*)(aptr0 + off);
            ra1 = *(const float4*)(aptr1 + off);
            rb0 = *(const float4*)(bptr0 + off);
            rb1 = *(const float4*)(bptr1 + off);
        }

        const float* A = sA + cur * TILE + ty * 4;
        const float* B = sB + cur * TILE + tx * 4;
        #pragma unroll 8
        for (int kk = 0; kk < BK; ++kk) {
            float4 a = *(const float4*)(A + kk * LDT);
            float4 b = *(const float4*)(B + kk * LDT);
            acc[0][0] = fmaf(a.x, b.x, acc[0][0]);
            acc[0][1] = fmaf(a.x, b.y, acc[0][1]);
            acc[0][2] = fmaf(a.x, b.z, acc[0][2]);
            acc[0][3] = fmaf(a.x, b.w, acc[0][3]);
            acc[1][0] = fmaf(a.y, b.x, acc[1][0]);
            acc[1][1] = fmaf(a.y, b.y, acc[1][1]);
            acc[1][2] = fmaf(a.y, b.z, acc[1][2]);
            acc[1][3] = fmaf(a.y, b.w, acc[1][3]);
            acc[2][0] = fmaf(a.z, b.x, acc[2][0]);
            acc[2][1] = fmaf(a.z, b.y, acc[2][1]);
            acc[2][2] = fmaf(a.z, b.z, acc[2][2]);
            acc[2][3] = fmaf(a.z, b.w, acc[2][3]);
            acc[3][0] = fmaf(a.w, b.x, acc[3][0]);
            acc[3][1] = fmaf(a.w, b.y, acc[3][1]);
            acc[3][2] = fmaf(a.w, b.z, acc[3][2]);
            acc[3][3] = fmaf(a.w, b.w, acc[3][3]);
        }

        if (more) store_tile(cur ^ 1);
        __syncthreads();
    }

    // ---- epilogue: bias add, write logits (global + LDS), top-2 + softmax ----
    const float4 bvec = *(const float4*)(bias + tx * 4);
    float* lvals = smem;  // logits tile [64][LDT]

    #pragma unroll
    for (int r = 0; r < 4; ++r) {
        float4 v;
        v.x = acc[r][0] + bvec.x;
        v.y = acc[r][1] + bvec.y;
        v.z = acc[r][2] + bvec.z;
        v.w = acc[r][3] + bvec.w;
        const int row = ty * 4 + r;
        *(float4*)(out + (size_t)(rowBase + row) * Edim + tx * 4) = v;
        *(float4*)(lvals + row * LDT + tx * 4) = v;
    }
    __syncthreads();

    if (tid < BM) {
        const float* lr = lvals + tid * LDT;
        // top-1: strict > keeps first occurrence (jax.lax.top_k tie rule)
        float m1 = lr[0]; int i1 = 0;
        #pragma unroll 8
        for (int e = 1; e < Edim; ++e) {
            float v = lr[e];
            if (v > m1) { m1 = v; i1 = e; }
        }
        // top-2: scan all e != i1, strict >
        float m2 = -INFINITY; int i2 = 0;
        #pragma unroll 8
        for (int e = 0; e < Edim; ++e) {
            if (e == i1) continue;
            float v = lr[e];
            if (v > m2) { m2 = v; i2 = e; }
        }
        // softmax over [m1, m2] (descending)
        const float t  = expf(m2 - m1);
        const float w1 = 1.0f / (1.0f + t);
        const float w2 = t * w1;

        const size_t ro    = (size_t)(rowBase + tid);
        const size_t base2 = (size_t)nrows * Edim;
        const size_t base3 = base2 + (size_t)nrows * 2;
        out[base2 + ro * 2 + 0] = (float)i1;
        out[base2 + ro * 2 + 1] = (float)i2;
        out[base3 + ro * 2 + 0] = w1;
        out[base3 + ro * 2 + 1] = w2;
    }
}

}  // namespace

extern "C" void kernel_launch(void* const* d_in, const int* in_sizes, int n_in,
                              void* d_out, int out_size, void* d_ws, size_t ws_size,
                              hipStream_t stream) {
    const float* hid  = (const float*)d_in[0];
    const float* Wm   = (const float*)d_in[1];
    const float* bias = (const float*)d_in[2];
    // d_in[3] is k (=2), fixed in this kernel.
    float* out = (float*)d_out;

    const int nrows = in_sizes[0] / Hdim;   // 16384
    dim3 grid(nrows / BM);                  // 256 blocks
    router_kernel<<<grid, 256, 0, stream>>>(hid, Wm, bias, out, nrows);
}